// Round 1
// baseline (7118.506 us; speedup 1.0000x reference)
//
#include <hip/hip_runtime.h>
#include <cstdint>
#include <cstddef>

typedef unsigned short u16;
typedef __attribute__((ext_vector_type(4))) float f32x4;
typedef __attribute__((ext_vector_type(8))) short s16x8;
typedef __attribute__((ext_vector_type(8))) unsigned short u16x8;

#define B_ 16
#define S_ 256
#define E_ 512
#define H_ 1024
#define V_ 32000
#define M_TOK (S_*B_)   // 4096 tokens, row m = s*16 + b

__device__ __forceinline__ u16 f2bf(float f) {
  union { float f; unsigned u; } x; x.f = f;
  unsigned r = x.u + 0x7fffu + ((x.u >> 16) & 1u);   // RNE, inputs are finite
  return (u16)(r >> 16);
}

// ---------------- fp32 -> bf16 converter (grid-stride, float4) ----------------
__global__ __launch_bounds__(256) void k_cvt(const float* __restrict__ src,
                                             u16* __restrict__ dst, int n4) {
  int i = blockIdx.x*blockDim.x + threadIdx.x;
  int stride = gridDim.x*blockDim.x;
  for (; i < n4; i += stride) {
    float4 v = reinterpret_cast<const float4*>(src)[i];
    ushort4 o;
    o.x = f2bf(v.x); o.y = f2bf(v.y); o.z = f2bf(v.z); o.w = f2bf(v.w);
    reinterpret_cast<ushort4*>(dst)[i] = o;
  }
}

// ---------------- embedding gather + convert: A1[m][k], m = s*16+b ----------------
__global__ __launch_bounds__(256) void k_embed(const int* __restrict__ ids,
                                               const float* __restrict__ emb,
                                               u16* __restrict__ A1) {
  int g = blockIdx.x*256 + threadIdx.x;      // one 8-elem chunk; total 4096*64
  int m = g >> 6;
  int c = g & 63;
  int s = m >> 4, b = m & 15;
  int id = ids[b*S_ + s];
  const float4* src = reinterpret_cast<const float4*>(emb + (size_t)id*E_ + (size_t)c*8);
  float4 v0 = src[0], v1 = src[1];
  u16x8 o;
  o[0]=f2bf(v0.x); o[1]=f2bf(v0.y); o[2]=f2bf(v0.z); o[3]=f2bf(v0.w);
  o[4]=f2bf(v1.x); o[5]=f2bf(v1.y); o[6]=f2bf(v1.z); o[7]=f2bf(v1.w);
  *reinterpret_cast<u16x8*>(A1 + (size_t)m*E_ + (size_t)c*8) = o;
}

// ---------------- bf16 B^T GEMM, 128x128 tile, m97-style ----------------
#define BM 128
#define BN 128
#define BK 32

__device__ __forceinline__ void gload_lds16(const u16* g, u16* l) {
  __builtin_amdgcn_global_load_lds(
      (const __attribute__((address_space(1))) void*)g,
      (__attribute__((address_space(3))) void*)l,
      16, 0, 0);
}

// FCMODE==0: C[row][col] = acc              (plain [M][N] fp32)
// FCMODE==1: C[(b*S+s)][col] = acc+bias[col] (row m=s*16+b remapped; N=V_)
template<int FCMODE>
__global__ __launch_bounds__(256)
void k_gemm(const u16* __restrict__ A, const u16* __restrict__ Bw,
            float* __restrict__ C, const float* __restrict__ bias,
            int M, int N, int K)
{
  __shared__ u16 lA[2][BM*BK];
  __shared__ u16 lB[2][BN*BK];
  const int tid = threadIdx.x;
  const int l = tid & 63, w = tid >> 6;
  const int m0 = blockIdx.y * BM, n0 = blockIdx.x * BN;
  const int wr = w >> 1, wc = w & 1;

  // staging: LDS 16B-chunk index L=(row<<2)|cc; content = global chunk cc ^ ((row>>1)&3)
  const int L0 = (w*2+0)*64 + l;
  const int L1 = (w*2+1)*64 + l;
  const int r0 = L0 >> 2, r1 = L1 >> 2;
  const int c0 = (L0 & 3) ^ ((r0 >> 1) & 3);
  const int c1 = (L1 & 3) ^ ((r1 >> 1) & 3);
  const u16* gA0 = A  + (size_t)(m0 + r0)*K + c0*8;
  const u16* gA1 = A  + (size_t)(m0 + r1)*K + c1*8;
  const u16* gB0 = Bw + (size_t)(n0 + r0)*K + c0*8;
  const u16* gB1 = Bw + (size_t)(n0 + r1)*K + c1*8;

  // frag ds_read offsets (u16 units); xor gives <=2-way bank aliasing (free)
  const int fr = l & 15;
  const int xc = (l >> 4) ^ ((fr >> 1) & 3);
  int aoff[4], boff[4];
#pragma unroll
  for (int f = 0; f < 4; ++f) {
    aoff[f] = (wr*64 + f*16 + fr) * BK + xc*8;
    boff[f] = (wc*64 + f*16 + fr) * BK + xc*8;
  }

  f32x4 acc[4][4] = {};
  const int KT = K / BK;

  gload_lds16(gA0, &lA[0][(w*2+0)*512]);
  gload_lds16(gA1, &lA[0][(w*2+1)*512]);
  gload_lds16(gB0, &lB[0][(w*2+0)*512]);
  gload_lds16(gB1, &lB[0][(w*2+1)*512]);
  __syncthreads();

  for (int kt = 0; kt < KT; ++kt) {
    const int buf = kt & 1;
    if (kt + 1 < KT) {
      const int koff = (kt+1)*BK;
      gload_lds16(gA0 + koff, &lA[buf^1][(w*2+0)*512]);
      gload_lds16(gA1 + koff, &lA[buf^1][(w*2+1)*512]);
      gload_lds16(gB0 + koff, &lB[buf^1][(w*2+0)*512]);
      gload_lds16(gB1 + koff, &lB[buf^1][(w*2+1)*512]);
    }
    s16x8 af[4], bq[4];
#pragma unroll
    for (int f = 0; f < 4; ++f) af[f] = *reinterpret_cast<const s16x8*>(&lA[buf][aoff[f]]);
#pragma unroll
    for (int f = 0; f < 4; ++f) bq[f] = *reinterpret_cast<const s16x8*>(&lB[buf][boff[f]]);
#pragma unroll
    for (int fm = 0; fm < 4; ++fm)
#pragma unroll
      for (int fn = 0; fn < 4; ++fn)
        acc[fm][fn] = __builtin_amdgcn_mfma_f32_16x16x32_bf16(af[fm], bq[fn], acc[fm][fn], 0, 0, 0);
    __syncthreads();   // drains vmcnt: next buf staged + all reads of buf done
  }

  const int rowb = (l >> 4) * 4;
  const int colb = l & 15;
#pragma unroll
  for (int fm = 0; fm < 4; ++fm) {
#pragma unroll
    for (int fn = 0; fn < 4; ++fn) {
      const int col = n0 + wc*64 + fn*16 + colb;
#pragma unroll
      for (int r = 0; r < 4; ++r) {
        const int row = m0 + wr*64 + fm*16 + rowb + r;
        float v = acc[fm][fn][r];
        if (FCMODE) {
          const int b = row & 15, s = row >> 4;
          C[((size_t)(b*S_ + s))*N + col] = v + bias[col];
        } else {
          C[(size_t)row*N + col] = v;
        }
      }
    }
  }
}

// ---------------- RNN scan: 16 persistent blocks, device-scope step barrier ----------------
// Block blk owns W rows [blk*64, blk*64+64) for ALL 16 batches.
// h stored bf16 in hs[m= t*16+b][i]; W frags read straight from L2 (slice stays hot).
__global__ __launch_bounds__(256)
void k_scan(const u16* __restrict__ W,    // [H][H] bf16
            const float* __restrict__ xp, // [M_TOK][H] fp32 input projection (no bias)
            const float* __restrict__ bih, const float* __restrict__ bhh,
            u16* __restrict__ hs,         // [M_TOK][H] bf16 out
            int* flags)                   // [S_] zeroed per launch
{
  const int tid = threadIdx.x;
  const int l = tid & 63, w = tid >> 6;
  const int blk = blockIdx.x;                  // 0..15
  const int rowA = blk*64 + w*16 + (l & 15);   // W row for A frag
  const int kc = l >> 4;                       // k chunk 0..3
  const int bcol = l & 15;                     // batch col (B operand)
  const int i0 = blk*64 + w*16 + (l >> 4)*4;   // this lane's 4 output rows

  float bc[4];
#pragma unroll
  for (int r = 0; r < 4; ++r) bc[r] = bih[i0+r] + bhh[i0+r];

  const u16* wrow = W + (size_t)rowA*H_ + kc*8;

  for (int t = 0; t < S_; ++t) {
    if (t > 0) {
      if (tid == 0) {
        while (__hip_atomic_load(&flags[t-1], __ATOMIC_RELAXED, __HIP_MEMORY_SCOPE_AGENT) < 16) {
          __builtin_amdgcn_s_sleep(1);
        }
      }
      __syncthreads();
      __threadfence();   // acquire: invalidate stale L1/L2 lines before reading h[t-1]
    }
    f32x4 acc = {0.f, 0.f, 0.f, 0.f};
    if (t > 0) {
      const u16* hrow = hs + ((size_t)(t-1)*B_ + bcol)*H_ + kc*8;
#pragma unroll 8
      for (int ks = 0; ks < 32; ++ks) {
        s16x8 a  = *reinterpret_cast<const s16x8*>(wrow + ks*32);
        s16x8 hb = *reinterpret_cast<const s16x8*>(hrow + ks*32);
        acc = __builtin_amdgcn_mfma_f32_16x16x32_bf16(a, hb, acc, 0, 0, 0);
      }
    }
    const int m = t*B_ + bcol;
    float4 xv = *reinterpret_cast<const float4*>(xp + (size_t)m*H_ + i0);
    ushort4 o;
    o.x = f2bf(tanhf(acc[0] + xv.x + bc[0]));
    o.y = f2bf(tanhf(acc[1] + xv.y + bc[1]));
    o.z = f2bf(tanhf(acc[2] + xv.z + bc[2]));
    o.w = f2bf(tanhf(acc[3] + xv.w + bc[3]));
    *reinterpret_cast<ushort4*>(hs + (size_t)m*H_ + i0) = o;
    __threadfence();     // release: slice visible device-wide
    __syncthreads();     // all threads of block fenced before the flag add
    if (tid == 0) {
      __hip_atomic_fetch_add(&flags[t], 1, __ATOMIC_RELEASE, __HIP_MEMORY_SCOPE_AGENT);
    }
  }
}

// ---------------- softmax, one row (32000) per wave, in-place ----------------
__global__ __launch_bounds__(256)
void k_softmax(float* __restrict__ out) {
  const int gw = (blockIdx.x*256 + threadIdx.x) >> 6;  // row 0..4095
  const int l = threadIdx.x & 63;
  float* row = out + (size_t)gw*V_;
  float mx = -3.4e38f;
  for (int it = 0; it < 125; ++it) {                    // 8000 float4 = 64*125
    float4 v = reinterpret_cast<const float4*>(row)[it*64 + l];
    mx = fmaxf(mx, fmaxf(fmaxf(v.x, v.y), fmaxf(v.z, v.w)));
  }
#pragma unroll
  for (int o = 32; o; o >>= 1) mx = fmaxf(mx, __shfl_xor(mx, o));
  float sum = 0.f;
  for (int it = 0; it < 125; ++it) {
    float4 v = reinterpret_cast<const float4*>(row)[it*64 + l];
    sum += expf(v.x - mx) + expf(v.y - mx) + expf(v.z - mx) + expf(v.w - mx);
  }
#pragma unroll
  for (int o = 32; o; o >>= 1) sum += __shfl_xor(sum, o);
  const float inv = 1.f / sum;
  for (int it = 0; it < 125; ++it) {
    float4 v = reinterpret_cast<const float4*>(row)[it*64 + l];
    float4 p;
    p.x = expf(v.x - mx)*inv; p.y = expf(v.y - mx)*inv;
    p.z = expf(v.z - mx)*inv; p.w = expf(v.w - mx)*inv;
    reinterpret_cast<float4*>(row)[it*64 + l] = p;
  }
}

extern "C" void kernel_launch(void* const* d_in, const int* in_sizes, int n_in,
                              void* d_out, int out_size, void* d_ws, size_t ws_size,
                              hipStream_t stream) {
  (void)in_sizes; (void)n_in; (void)out_size; (void)ws_size;
  const int*   x_ids = (const int*)  d_in[0];
  const float* emb   = (const float*)d_in[1];
  const float* Wih1  = (const float*)d_in[2];
  const float* bih1  = (const float*)d_in[3];
  const float* Whh1  = (const float*)d_in[4];
  const float* bhh1  = (const float*)d_in[5];
  const float* Wih2  = (const float*)d_in[6];
  const float* bih2  = (const float*)d_in[7];
  const float* Whh2  = (const float*)d_in[8];
  const float* bhh2  = (const float*)d_in[9];
  const float* Wfc   = (const float*)d_in[10];
  const float* bfc   = (const float*)d_in[11];
  float* out = (float*)d_out;

  char* ws = (char*)d_ws;
  size_t off = 0;
  auto alloc = [&](size_t bytes) {
    char* p = ws + off; off += (bytes + 255) & ~(size_t)255; return p;
  };
  int* flags  = (int*) alloc(2048);                       // 512 ints, layer1 + layer2
  u16* A1     = (u16*) alloc((size_t)M_TOK*E_*2);
  u16* Wih1b  = (u16*) alloc((size_t)H_*E_*2);
  u16* Whh1b  = (u16*) alloc((size_t)H_*H_*2);
  u16* Wih2b  = (u16*) alloc((size_t)H_*H_*2);
  u16* Whh2b  = (u16*) alloc((size_t)H_*H_*2);
  u16* Wfcb   = (u16*) alloc((size_t)V_*H_*2);
  float* x1   = (float*)alloc((size_t)M_TOK*H_*4);
  u16* h1s    = (u16*) alloc((size_t)M_TOK*H_*2);
  float* x2   = (float*)alloc((size_t)M_TOK*H_*4);
  u16* h2s    = (u16*) alloc((size_t)M_TOK*H_*2);
  // total ws use ~122 MiB

  hipMemsetAsync(flags, 0, 2048, stream);                 // replay-safe flag reset

  k_cvt<<<256,  256, 0, stream>>>(Wih1, Wih1b, H_*E_/4);
  k_cvt<<<256,  256, 0, stream>>>(Whh1, Whh1b, H_*H_/4);
  k_cvt<<<256,  256, 0, stream>>>(Wih2, Wih2b, H_*H_/4);
  k_cvt<<<256,  256, 0, stream>>>(Whh2, Whh2b, H_*H_/4);
  k_cvt<<<2048, 256, 0, stream>>>(Wfc,  Wfcb,  V_*H_/4);
  k_embed<<<M_TOK*64/256, 256, 0, stream>>>(x_ids, emb, A1);

  k_gemm<0><<<dim3(H_/BN, M_TOK/BM), 256, 0, stream>>>(A1,  Wih1b, x1, nullptr, M_TOK, H_, E_);
  k_scan<<<16, 256, 0, stream>>>(Whh1b, x1, bih1, bhh1, h1s, flags);
  k_gemm<0><<<dim3(H_/BN, M_TOK/BM), 256, 0, stream>>>(h1s, Wih2b, x2, nullptr, M_TOK, H_, H_);
  k_scan<<<16, 256, 0, stream>>>(Whh2b, x2, bih2, bhh2, h2s, flags + 256);
  k_gemm<1><<<dim3(V_/BN, M_TOK/BM), 256, 0, stream>>>(h2s, Wfcb, out, bfc, M_TOK, V_, H_);
  k_softmax<<<M_TOK/4, 256, 0, stream>>>(out);
}

// Round 2
// 2020.398 us; speedup vs baseline: 3.5233x; 3.5233x over previous
//
#include <hip/hip_runtime.h>
#include <cstdint>
#include <cstddef>

typedef unsigned short u16;
typedef __attribute__((ext_vector_type(4))) float f32x4;
typedef __attribute__((ext_vector_type(8))) short s16x8;
typedef __attribute__((ext_vector_type(8))) unsigned short u16x8;
typedef __attribute__((ext_vector_type(4))) unsigned short u16x4;

#define B_ 16
#define S_ 256
#define E_ 512
#define H_ 1024
#define V_ 32000
#define M_TOK (S_*B_)   // 4096 tokens, row m = s*16 + b

__device__ __forceinline__ u16 f2bf(float f) {
  union { float f; unsigned u; } x; x.f = f;
  unsigned r = x.u + 0x7fffu + ((x.u >> 16) & 1u);   // RNE, inputs are finite
  return (u16)(r >> 16);
}

// ---- cache-bypassing (LLC-coherent) ops: no wbl2/inv fences needed ----
__device__ __forceinline__ void sc_load16(s16x8& d, const u16* p) {
  asm volatile("global_load_dwordx4 %0, %1, off sc0 sc1" : "=v"(d) : "v"(p));
}
__device__ __forceinline__ void sc_store8(u16* p, u16x4 v) {
  asm volatile("global_store_dwordx2 %0, %1, off sc0 sc1" :: "v"(p), "v"(v) : "memory");
}
__device__ __forceinline__ void wait_vm0() {
  asm volatile("s_waitcnt vmcnt(0)" ::: "memory");
}

// ---------------- fp32 -> bf16 converter ----------------
__global__ __launch_bounds__(256) void k_cvt(const float* __restrict__ src,
                                             u16* __restrict__ dst, int n4) {
  int i = blockIdx.x*blockDim.x + threadIdx.x;
  int stride = gridDim.x*blockDim.x;
  for (; i < n4; i += stride) {
    float4 v = reinterpret_cast<const float4*>(src)[i];
    ushort4 o;
    o.x = f2bf(v.x); o.y = f2bf(v.y); o.z = f2bf(v.z); o.w = f2bf(v.w);
    reinterpret_cast<ushort4*>(dst)[i] = o;
  }
}

// ---------------- embedding gather + convert: A1[m][k], m = s*16+b ----------------
__global__ __launch_bounds__(256) void k_embed(const int* __restrict__ ids,
                                               const float* __restrict__ emb,
                                               u16* __restrict__ A1) {
  int g = blockIdx.x*256 + threadIdx.x;
  int m = g >> 6;
  int c = g & 63;
  int s = m >> 4, b = m & 15;
  int id = ids[b*S_ + s];
  const float4* src = reinterpret_cast<const float4*>(emb + (size_t)id*E_ + (size_t)c*8);
  float4 v0 = src[0], v1 = src[1];
  u16x8 o;
  o[0]=f2bf(v0.x); o[1]=f2bf(v0.y); o[2]=f2bf(v0.z); o[3]=f2bf(v0.w);
  o[4]=f2bf(v1.x); o[5]=f2bf(v1.y); o[6]=f2bf(v1.z); o[7]=f2bf(v1.w);
  *reinterpret_cast<u16x8*>(A1 + (size_t)m*E_ + (size_t)c*8) = o;
}

// ---------------- bf16 B^T GEMM, 128x128 tile ----------------
#define BM 128
#define BN 128
#define BK 32

__device__ __forceinline__ void gload_lds16(const u16* g, u16* l) {
  __builtin_amdgcn_global_load_lds(
      (const __attribute__((address_space(1))) void*)g,
      (__attribute__((address_space(3))) void*)l,
      16, 0, 0);
}

template<int FCMODE>
__global__ __launch_bounds__(256)
void k_gemm(const u16* __restrict__ A, const u16* __restrict__ Bw,
            float* __restrict__ C, const float* __restrict__ bias,
            int M, int N, int K)
{
  __shared__ u16 lA[2][BM*BK];
  __shared__ u16 lB[2][BN*BK];
  const int tid = threadIdx.x;
  const int l = tid & 63, w = tid >> 6;
  const int m0 = blockIdx.y * BM, n0 = blockIdx.x * BN;
  const int wr = w >> 1, wc = w & 1;

  const int L0 = (w*2+0)*64 + l;
  const int L1 = (w*2+1)*64 + l;
  const int r0 = L0 >> 2, r1 = L1 >> 2;
  const int c0 = (L0 & 3) ^ ((r0 >> 1) & 3);
  const int c1 = (L1 & 3) ^ ((r1 >> 1) & 3);
  const u16* gA0 = A  + (size_t)(m0 + r0)*K + c0*8;
  const u16* gA1 = A  + (size_t)(m0 + r1)*K + c1*8;
  const u16* gB0 = Bw + (size_t)(n0 + r0)*K + c0*8;
  const u16* gB1 = Bw + (size_t)(n0 + r1)*K + c1*8;

  const int fr = l & 15;
  const int xc = (l >> 4) ^ ((fr >> 1) & 3);
  int aoff[4], boff[4];
#pragma unroll
  for (int f = 0; f < 4; ++f) {
    aoff[f] = (wr*64 + f*16 + fr) * BK + xc*8;
    boff[f] = (wc*64 + f*16 + fr) * BK + xc*8;
  }

  f32x4 acc[4][4] = {};
  const int KT = K / BK;

  gload_lds16(gA0, &lA[0][(w*2+0)*512]);
  gload_lds16(gA1, &lA[0][(w*2+1)*512]);
  gload_lds16(gB0, &lB[0][(w*2+0)*512]);
  gload_lds16(gB1, &lB[0][(w*2+1)*512]);
  __syncthreads();

  for (int kt = 0; kt < KT; ++kt) {
    const int buf = kt & 1;
    if (kt + 1 < KT) {
      const int koff = (kt+1)*BK;
      gload_lds16(gA0 + koff, &lA[buf^1][(w*2+0)*512]);
      gload_lds16(gA1 + koff, &lA[buf^1][(w*2+1)*512]);
      gload_lds16(gB0 + koff, &lB[buf^1][(w*2+0)*512]);
      gload_lds16(gB1 + koff, &lB[buf^1][(w*2+1)*512]);
    }
    s16x8 af[4], bq[4];
#pragma unroll
    for (int f = 0; f < 4; ++f) af[f] = *reinterpret_cast<const s16x8*>(&lA[buf][aoff[f]]);
#pragma unroll
    for (int f = 0; f < 4; ++f) bq[f] = *reinterpret_cast<const s16x8*>(&lB[buf][boff[f]]);
#pragma unroll
    for (int fm = 0; fm < 4; ++fm)
#pragma unroll
      for (int fn = 0; fn < 4; ++fn)
        acc[fm][fn] = __builtin_amdgcn_mfma_f32_16x16x32_bf16(af[fm], bq[fn], acc[fm][fn], 0, 0, 0);
    __syncthreads();
  }

  const int rowb = (l >> 4) * 4;
  const int colb = l & 15;
#pragma unroll
  for (int fm = 0; fm < 4; ++fm) {
#pragma unroll
    for (int fn = 0; fn < 4; ++fn) {
      const int col = n0 + wc*64 + fn*16 + colb;
#pragma unroll
      for (int r = 0; r < 4; ++r) {
        const int row = m0 + wr*64 + fm*16 + rowb + r;
        float v = acc[fm][fn][r];
        if (FCMODE) {
          const int b = row & 15, s = row >> 4;
          C[((size_t)(b*S_ + s))*N + col] = v + bias[col];
        } else {
          C[(size_t)row*N + col] = v;
        }
      }
    }
  }
}

// ---------------- fused 2-layer RNN scan, 32 persistent blocks ----------------
// blockIdx even -> layer 1 (blk = idx>>1), odd -> layer 2. Layer 2 runs one
// step behind layer 1 and computes its own input projection (W_ih2 * h1[t]).
// h exchanged via sc0/sc1 (LLC-coherent) ops; W held in VGPRs; h staged in LDS.
__global__ __launch_bounds__(256, 1)
void k_scan2(const u16* __restrict__ Whh1, const u16* __restrict__ Wih2,
             const u16* __restrict__ Whh2, const float* __restrict__ x1,
             const float* __restrict__ bih1, const float* __restrict__ bhh1,
             const float* __restrict__ bih2, const float* __restrict__ bhh2,
             u16* __restrict__ h1s, u16* __restrict__ h2s,
             int* __restrict__ flags1, int* __restrict__ flags2)
{
  __shared__ u16 sh[2][B_*H_];          // two 32 KiB swizzled h buffers
  const int tid = threadIdx.x;
  const int l = tid & 63, w = tid >> 6;
  const int layer = blockIdx.x & 1;
  const int blk = blockIdx.x >> 1;              // 0..15
  const int rowA = blk*64 + w*16 + (l & 15);    // W row (A frag)
  const int kc = l >> 4;                        // k chunk 0..3
  const int bcol = l & 15;                      // batch col (B frag / C col)
  const int i0 = blk*64 + w*16 + (l >> 4)*4;    // lane's 4 output rows
  const int sw = (bcol & 7) << 4;               // LDS read swizzle

  auto hfrag = [&](int sb, int ks) -> s16x8 {
    return *reinterpret_cast<const s16x8*>(
        reinterpret_cast<const char*>(&sh[sb][0]) +
        bcol*2048 + (((kc*16) + ks*64) ^ sw));
  };

  if (layer == 0) {
    float bc[4];
#pragma unroll
    for (int r = 0; r < 4; ++r) bc[r] = bih1[i0+r] + bhh1[i0+r];
    s16x8 wf[32];
    const u16* wp = Whh1 + (size_t)rowA*H_ + kc*8;
#pragma unroll
    for (int ks = 0; ks < 32; ++ks) wf[ks] = *reinterpret_cast<const s16x8*>(wp + ks*32);

    float4 xv = *reinterpret_cast<const float4*>(x1 + (size_t)bcol*H_ + i0);

    for (int t = 0; t < S_; ++t) {
      f32x4 a0 = {}, a1 = {}, a2 = {}, a3 = {};
      if (t > 0) {
        if (tid == 0)
          while (__hip_atomic_load(flags1 + (t-1), __ATOMIC_RELAXED, __HIP_MEMORY_SCOPE_AGENT) < 16) {}
        __syncthreads();
        s16x8 stg[8];
        const u16* src = h1s + (size_t)(t-1)*(B_*H_);
#pragma unroll
        for (int r = 0; r < 8; ++r) sc_load16(stg[r], src + (tid + r*256)*8);
        wait_vm0();
#pragma unroll
        for (int r = 0; r < 8; ++r) {
          int idx8 = tid + r*256;
          int bt = idx8 >> 7, c8 = idx8 & 127;
          *reinterpret_cast<s16x8*>(reinterpret_cast<char*>(&sh[0][0]) +
              bt*2048 + ((c8*16) ^ ((bt & 7) << 4))) = stg[r];
        }
        __syncthreads();
#pragma unroll
        for (int ks = 0; ks < 32; ks += 4) {
          a0 = __builtin_amdgcn_mfma_f32_16x16x32_bf16(wf[ks+0], hfrag(0, ks+0), a0, 0, 0, 0);
          a1 = __builtin_amdgcn_mfma_f32_16x16x32_bf16(wf[ks+1], hfrag(0, ks+1), a1, 0, 0, 0);
          a2 = __builtin_amdgcn_mfma_f32_16x16x32_bf16(wf[ks+2], hfrag(0, ks+2), a2, 0, 0, 0);
          a3 = __builtin_amdgcn_mfma_f32_16x16x32_bf16(wf[ks+3], hfrag(0, ks+3), a3, 0, 0, 0);
        }
      }
      float4 xvn = xv;
      if (t + 1 < S_)
        xvn = *reinterpret_cast<const float4*>(x1 + (size_t)((t+1)*B_ + bcol)*H_ + i0);
      f32x4 tot = (a0 + a1) + (a2 + a3);
      u16x4 o;
      o[0] = f2bf(tanhf(tot[0] + xv.x + bc[0]));
      o[1] = f2bf(tanhf(tot[1] + xv.y + bc[1]));
      o[2] = f2bf(tanhf(tot[2] + xv.z + bc[2]));
      o[3] = f2bf(tanhf(tot[3] + xv.w + bc[3]));
      sc_store8(h1s + (size_t)(t*B_ + bcol)*H_ + i0, o);
      wait_vm0();
      __syncthreads();
      if (tid == 0)
        __hip_atomic_fetch_add(flags1 + t, 1, __ATOMIC_RELAXED, __HIP_MEMORY_SCOPE_AGENT);
      xv = xvn;
    }
  } else {
    float bc[4];
#pragma unroll
    for (int r = 0; r < 4; ++r) bc[r] = bih2[i0+r] + bhh2[i0+r];
    s16x8 wfi[32], wfh[32];
    const u16* wp = Wih2 + (size_t)rowA*H_ + kc*8;
    const u16* wq = Whh2 + (size_t)rowA*H_ + kc*8;
#pragma unroll
    for (int ks = 0; ks < 32; ++ks) wfi[ks] = *reinterpret_cast<const s16x8*>(wp + ks*32);
#pragma unroll
    for (int ks = 0; ks < 32; ++ks) wfh[ks] = *reinterpret_cast<const s16x8*>(wq + ks*32);

    for (int t = 0; t < S_; ++t) {
      if (tid == 0) {
        while (__hip_atomic_load(flags1 + t, __ATOMIC_RELAXED, __HIP_MEMORY_SCOPE_AGENT) < 16) {}
        if (t > 0)
          while (__hip_atomic_load(flags2 + (t-1), __ATOMIC_RELAXED, __HIP_MEMORY_SCOPE_AGENT) < 16) {}
      }
      __syncthreads();
      s16x8 stg[16];
      const u16* s1 = h1s + (size_t)t*(B_*H_);
#pragma unroll
      for (int r = 0; r < 8; ++r) sc_load16(stg[r], s1 + (tid + r*256)*8);
      if (t > 0) {
        const u16* s2 = h2s + (size_t)(t-1)*(B_*H_);
#pragma unroll
        for (int r = 0; r < 8; ++r) sc_load16(stg[8+r], s2 + (tid + r*256)*8);
      }
      wait_vm0();
#pragma unroll
      for (int r = 0; r < 8; ++r) {
        int idx8 = tid + r*256;
        int bt = idx8 >> 7, c8 = idx8 & 127;
        int byte = bt*2048 + ((c8*16) ^ ((bt & 7) << 4));
        *reinterpret_cast<s16x8*>(reinterpret_cast<char*>(&sh[0][0]) + byte) = stg[r];
      }
      if (t > 0) {
#pragma unroll
        for (int r = 0; r < 8; ++r) {
          int idx8 = tid + r*256;
          int bt = idx8 >> 7, c8 = idx8 & 127;
          int byte = bt*2048 + ((c8*16) ^ ((bt & 7) << 4));
          *reinterpret_cast<s16x8*>(reinterpret_cast<char*>(&sh[1][0]) + byte) = stg[8+r];
        }
      }
      __syncthreads();
      f32x4 a0 = {}, a1 = {}, a2 = {}, a3 = {};
#pragma unroll
      for (int ks = 0; ks < 32; ks += 4) {
        a0 = __builtin_amdgcn_mfma_f32_16x16x32_bf16(wfi[ks+0], hfrag(0, ks+0), a0, 0, 0, 0);
        a1 = __builtin_amdgcn_mfma_f32_16x16x32_bf16(wfi[ks+1], hfrag(0, ks+1), a1, 0, 0, 0);
        a2 = __builtin_amdgcn_mfma_f32_16x16x32_bf16(wfi[ks+2], hfrag(0, ks+2), a2, 0, 0, 0);
        a3 = __builtin_amdgcn_mfma_f32_16x16x32_bf16(wfi[ks+3], hfrag(0, ks+3), a3, 0, 0, 0);
      }
      if (t > 0) {
#pragma unroll
        for (int ks = 0; ks < 32; ks += 4) {
          a0 = __builtin_amdgcn_mfma_f32_16x16x32_bf16(wfh[ks+0], hfrag(1, ks+0), a0, 0, 0, 0);
          a1 = __builtin_amdgcn_mfma_f32_16x16x32_bf16(wfh[ks+1], hfrag(1, ks+1), a1, 0, 0, 0);
          a2 = __builtin_amdgcn_mfma_f32_16x16x32_bf16(wfh[ks+2], hfrag(1, ks+2), a2, 0, 0, 0);
          a3 = __builtin_amdgcn_mfma_f32_16x16x32_bf16(wfh[ks+3], hfrag(1, ks+3), a3, 0, 0, 0);
        }
      }
      f32x4 tot = (a0 + a1) + (a2 + a3);
      u16x4 o;
      o[0] = f2bf(tanhf(tot[0] + bc[0]));
      o[1] = f2bf(tanhf(tot[1] + bc[1]));
      o[2] = f2bf(tanhf(tot[2] + bc[2]));
      o[3] = f2bf(tanhf(tot[3] + bc[3]));
      sc_store8(h2s + (size_t)(t*B_ + bcol)*H_ + i0, o);
      wait_vm0();
      __syncthreads();
      if (tid == 0)
        __hip_atomic_fetch_add(flags2 + t, 1, __ATOMIC_RELAXED, __HIP_MEMORY_SCOPE_AGENT);
    }
  }
}

// ---------------- online softmax, one row (32000) per wave, in-place ----------------
__global__ __launch_bounds__(256)
void k_softmax(float* __restrict__ out) {
  const int gw = (blockIdx.x*256 + threadIdx.x) >> 6;
  const int l = threadIdx.x & 63;
  float* row = out + (size_t)gw*V_;
  float m = -3.4e38f, s = 0.f;
  for (int it = 0; it < 125; ++it) {
    float4 v = reinterpret_cast<const float4*>(row)[it*64 + l];
    float cm = fmaxf(fmaxf(v.x, v.y), fmaxf(v.z, v.w));
    float nm = fmaxf(m, cm);
    s = s*__expf(m - nm) + __expf(v.x-nm) + __expf(v.y-nm) + __expf(v.z-nm) + __expf(v.w-nm);
    m = nm;
  }
#pragma unroll
  for (int o = 32; o; o >>= 1) {
    float m2 = __shfl_xor(m, o), s2 = __shfl_xor(s, o);
    float nm = fmaxf(m, m2);
    s = s*__expf(m - nm) + s2*__expf(m2 - nm);
    m = nm;
  }
  const float inv = 1.f / s;
  for (int it = 0; it < 125; ++it) {
    float4 v = reinterpret_cast<const float4*>(row)[it*64 + l];
    float4 p;
    p.x = __expf(v.x - m)*inv; p.y = __expf(v.y - m)*inv;
    p.z = __expf(v.z - m)*inv; p.w = __expf(v.w - m)*inv;
    reinterpret_cast<float4*>(row)[it*64 + l] = p;
  }
}

extern "C" void kernel_launch(void* const* d_in, const int* in_sizes, int n_in,
                              void* d_out, int out_size, void* d_ws, size_t ws_size,
                              hipStream_t stream) {
  (void)in_sizes; (void)n_in; (void)out_size; (void)ws_size;
  const int*   x_ids = (const int*)  d_in[0];
  const float* emb   = (const float*)d_in[1];
  const float* Wih1  = (const float*)d_in[2];
  const float* bih1  = (const float*)d_in[3];
  const float* Whh1  = (const float*)d_in[4];
  const float* bhh1  = (const float*)d_in[5];
  const float* Wih2  = (const float*)d_in[6];
  const float* bih2  = (const float*)d_in[7];
  const float* Whh2  = (const float*)d_in[8];
  const float* bhh2  = (const float*)d_in[9];
  const float* Wfc   = (const float*)d_in[10];
  const float* bfc   = (const float*)d_in[11];
  float* out = (float*)d_out;

  char* ws = (char*)d_ws;
  size_t off = 0;
  auto alloc = [&](size_t bytes) {
    char* p = ws + off; off += (bytes + 255) & ~(size_t)255; return p;
  };
  int* flags  = (int*) alloc(2048);
  u16* A1     = (u16*) alloc((size_t)M_TOK*E_*2);
  u16* Wih1b  = (u16*) alloc((size_t)H_*E_*2);
  u16* Whh1b  = (u16*) alloc((size_t)H_*H_*2);
  u16* Wih2b  = (u16*) alloc((size_t)H_*H_*2);
  u16* Whh2b  = (u16*) alloc((size_t)H_*H_*2);
  u16* Wfcb   = (u16*) alloc((size_t)V_*H_*2);
  float* x1   = (float*)alloc((size_t)M_TOK*H_*4);
  u16* h1s    = (u16*) alloc((size_t)M_TOK*H_*2);
  u16* h2s    = (u16*) alloc((size_t)M_TOK*H_*2);

  hipMemsetAsync(flags, 0, 2048, stream);

  k_cvt<<<256,  256, 0, stream>>>(Wih1, Wih1b, H_*E_/4);
  k_cvt<<<256,  256, 0, stream>>>(Whh1, Whh1b, H_*H_/4);
  k_cvt<<<256,  256, 0, stream>>>(Wih2, Wih2b, H_*H_/4);
  k_cvt<<<256,  256, 0, stream>>>(Whh2, Whh2b, H_*H_/4);
  k_cvt<<<2048, 256, 0, stream>>>(Wfc,  Wfcb,  V_*H_/4);
  k_embed<<<M_TOK*64/256, 256, 0, stream>>>(x_ids, emb, A1);

  k_gemm<0><<<dim3(H_/BN, M_TOK/BM), 256, 0, stream>>>(A1, Wih1b, x1, nullptr, M_TOK, H_, E_);
  k_scan2<<<32, 256, 0, stream>>>(Whh1b, Wih2b, Whh2b, x1,
                                  bih1, bhh1, bih2, bhh2, h1s, h2s,
                                  flags, flags + 256);
  k_gemm<1><<<dim3(V_/BN, M_TOK/BM), 256, 0, stream>>>(h2s, Wfcb, out, bfc, M_TOK, V_, H_);
  k_softmax<<<M_TOK/4, 256, 0, stream>>>(out);
}

// Round 3
// 1885.933 us; speedup vs baseline: 3.7745x; 1.0713x over previous
//
#include <hip/hip_runtime.h>
#include <cstdint>
#include <cstddef>

typedef unsigned short u16;
typedef __attribute__((ext_vector_type(4))) float f32x4;
typedef __attribute__((ext_vector_type(8))) short s16x8;
typedef __attribute__((ext_vector_type(8))) unsigned short u16x8;
typedef __attribute__((ext_vector_type(4))) unsigned short u16x4;

#define B_ 16
#define S_ 256
#define E_ 512
#define H_ 1024
#define V_ 32000
#define M_TOK (S_*B_)   // 4096 tokens, row m = s*16 + b

__device__ __forceinline__ u16 f2bf(float f) {
  union { float f; unsigned u; } x; x.f = f;
  unsigned r = x.u + 0x7fffu + ((x.u >> 16) & 1u);   // RNE, inputs finite
  return (u16)(r >> 16);
}

// ---- LLC-coherent (device-scope, cache-bypassing) ops ----
__device__ __forceinline__ void sc_load16(s16x8& d, const u16* p) {
  asm volatile("global_load_dwordx4 %0, %1, off sc0 sc1" : "=v"(d) : "v"(p));
}
__device__ __forceinline__ void sc_load16f(f32x4& d, const float* p) {
  asm volatile("global_load_dwordx4 %0, %1, off sc0 sc1" : "=v"(d) : "v"(p));
}
__device__ __forceinline__ void sc_store8(u16* p, u16x4 v) {
  asm volatile("global_store_dwordx2 %0, %1, off sc0 sc1" :: "v"(p), "v"(v) : "memory");
}
__device__ __forceinline__ void sc_store16f(float* p, f32x4 v) {
  asm volatile("global_store_dwordx4 %0, %1, off sc0 sc1" :: "v"(p), "v"(v) : "memory");
}
__device__ __forceinline__ void wait_vm0() {
  asm volatile("s_waitcnt vmcnt(0)" ::: "memory");
}

// ---------------- fp32 -> bf16 converter ----------------
__global__ __launch_bounds__(256) void k_cvt(const float* __restrict__ src,
                                             u16* __restrict__ dst, int n4) {
  int i = blockIdx.x*blockDim.x + threadIdx.x;
  int stride = gridDim.x*blockDim.x;
  for (; i < n4; i += stride) {
    float4 v = reinterpret_cast<const float4*>(src)[i];
    ushort4 o;
    o.x = f2bf(v.x); o.y = f2bf(v.y); o.z = f2bf(v.z); o.w = f2bf(v.w);
    reinterpret_cast<ushort4*>(dst)[i] = o;
  }
}

// ---------------- embedding gather + convert: A1[m][k], m = s*16+b ----------------
__global__ __launch_bounds__(256) void k_embed(const int* __restrict__ ids,
                                               const float* __restrict__ emb,
                                               u16* __restrict__ A1) {
  int g = blockIdx.x*256 + threadIdx.x;
  int m = g >> 6;
  int c = g & 63;
  int s = m >> 4, b = m & 15;
  int id = ids[b*S_ + s];
  const float4* src = reinterpret_cast<const float4*>(emb + (size_t)id*E_ + (size_t)c*8);
  float4 v0 = src[0], v1 = src[1];
  u16x8 o;
  o[0]=f2bf(v0.x); o[1]=f2bf(v0.y); o[2]=f2bf(v0.z); o[3]=f2bf(v0.w);
  o[4]=f2bf(v1.x); o[5]=f2bf(v1.y); o[6]=f2bf(v1.z); o[7]=f2bf(v1.w);
  *reinterpret_cast<u16x8*>(A1 + (size_t)m*E_ + (size_t)c*8) = o;
}

// ---------------- bf16 B^T GEMM, 128x128 tile, XCD-swizzled ----------------
#define BM 128
#define BN 128
#define BK 32

__device__ __forceinline__ void gload_lds16(const u16* g, u16* l) {
  __builtin_amdgcn_global_load_lds(
      (const __attribute__((address_space(1))) void*)g,
      (__attribute__((address_space(3))) void*)l,
      16, 0, 0);
}

template<int FCMODE>
__global__ __launch_bounds__(256)
void k_gemm(const u16* __restrict__ A, const u16* __restrict__ Bw,
            float* __restrict__ C, const float* __restrict__ bias,
            int M, int N, int K)
{
  __shared__ u16 lA[2][BM*BK];
  __shared__ u16 lB[2][BN*BK];
  const int tid = threadIdx.x;
  const int l = tid & 63, w = tid >> 6;

  // XCD-aware swizzle (grid size divisible by 8 for both call sites)
  const int nwg = gridDim.x * gridDim.y;
  int flat = blockIdx.y * gridDim.x + blockIdx.x;
  flat = (flat & 7) * (nwg >> 3) + (flat >> 3);
  const int m0 = (flat / gridDim.x) * BM;
  const int n0 = (flat % gridDim.x) * BN;

  const int wr = w >> 1, wc = w & 1;

  const int L0 = (w*2+0)*64 + l;
  const int L1 = (w*2+1)*64 + l;
  const int r0 = L0 >> 2, r1 = L1 >> 2;
  const int c0 = (L0 & 3) ^ ((r0 >> 1) & 3);
  const int c1 = (L1 & 3) ^ ((r1 >> 1) & 3);
  const u16* gA0 = A  + (size_t)(m0 + r0)*K + c0*8;
  const u16* gA1 = A  + (size_t)(m0 + r1)*K + c1*8;
  const u16* gB0 = Bw + (size_t)(n0 + r0)*K + c0*8;
  const u16* gB1 = Bw + (size_t)(n0 + r1)*K + c1*8;

  const int fr = l & 15;
  const int xc = (l >> 4) ^ ((fr >> 1) & 3);
  int aoff[4], boff[4];
#pragma unroll
  for (int f = 0; f < 4; ++f) {
    aoff[f] = (wr*64 + f*16 + fr) * BK + xc*8;
    boff[f] = (wc*64 + f*16 + fr) * BK + xc*8;
  }

  f32x4 acc[4][4] = {};
  const int KT = K / BK;

  gload_lds16(gA0, &lA[0][(w*2+0)*512]);
  gload_lds16(gA1, &lA[0][(w*2+1)*512]);
  gload_lds16(gB0, &lB[0][(w*2+0)*512]);
  gload_lds16(gB1, &lB[0][(w*2+1)*512]);
  __syncthreads();

  for (int kt = 0; kt < KT; ++kt) {
    const int buf = kt & 1;
    if (kt + 1 < KT) {
      const int koff = (kt+1)*BK;
      gload_lds16(gA0 + koff, &lA[buf^1][(w*2+0)*512]);
      gload_lds16(gA1 + koff, &lA[buf^1][(w*2+1)*512]);
      gload_lds16(gB0 + koff, &lB[buf^1][(w*2+0)*512]);
      gload_lds16(gB1 + koff, &lB[buf^1][(w*2+1)*512]);
    }
    s16x8 af[4], bq[4];
#pragma unroll
    for (int f = 0; f < 4; ++f) af[f] = *reinterpret_cast<const s16x8*>(&lA[buf][aoff[f]]);
#pragma unroll
    for (int f = 0; f < 4; ++f) bq[f] = *reinterpret_cast<const s16x8*>(&lB[buf][boff[f]]);
#pragma unroll
    for (int fm = 0; fm < 4; ++fm)
#pragma unroll
      for (int fn = 0; fn < 4; ++fn)
        acc[fm][fn] = __builtin_amdgcn_mfma_f32_16x16x32_bf16(af[fm], bq[fn], acc[fm][fn], 0, 0, 0);
    __syncthreads();
  }

  const int rowb = (l >> 4) * 4;
  const int colb = l & 15;
#pragma unroll
  for (int fm = 0; fm < 4; ++fm) {
#pragma unroll
    for (int fn = 0; fn < 4; ++fn) {
      const int col = n0 + wc*64 + fn*16 + colb;
#pragma unroll
      for (int r = 0; r < 4; ++r) {
        const int row = m0 + wr*64 + fm*16 + rowb + r;
        float v = acc[fm][fn][r];
        if (FCMODE) {
          const int b = row & 15, s = row >> 4;
          C[((size_t)(b*S_ + s))*N + col] = v + bias[col];
        } else {
          C[(size_t)row*N + col] = v;
        }
      }
    }
  }
}

// ---------------- fused 2-layer scan: 48 blocks, 3 roles, sentinel-poll ----------------
// role 0 (blk 0-15):  h1[t] = tanh(Whh1·h1[t-1] + x1[t] + b1)
// role 1 (blk 16-31): u[t]  = Wih2·h1[t] + b2          (pipelined projection)
// role 2 (blk 32-47): h2[t] = tanh(Whh2·h2[t-1] + u[t])
// All exchange buffers are NaN-poisoned (0xFF memset) per launch; consumers
// poll the data itself via sc0/sc1 loads (tanh/MFMA outputs are never NaN).
__global__ __launch_bounds__(256, 1)
void k_scan3(const u16* __restrict__ Whh1, const u16* __restrict__ Wih2,
             const u16* __restrict__ Whh2, const float* __restrict__ x1,
             const float* __restrict__ bih1, const float* __restrict__ bhh1,
             const float* __restrict__ bih2, const float* __restrict__ bhh2,
             u16* __restrict__ h1s, u16* __restrict__ h2s,
             float* __restrict__ u2s)
{
  __shared__ u16 sh[B_*H_];                     // 32 KiB swizzled h stage
  const int tid = threadIdx.x;
  const int l = tid & 63, w = tid >> 6;
  const int role = blockIdx.x >> 4;             // 0,1,2
  const int blk  = blockIdx.x & 15;
  const int rowA = blk*64 + w*16 + (l & 15);    // W row (A frag)
  const int kc = l >> 4;                        // k chunk 0..3
  const int bcol = l & 15;                      // batch col
  const int i0 = blk*64 + w*16 + kc*4;          // lane's 4 output rows

  const u16* Wsel = (role == 0) ? Whh1 : (role == 1) ? Wih2 : Whh2;
  s16x8 wf[32];                                 // 128 VGPR: whole W slice resident
  {
    const u16* wp = Wsel + (size_t)rowA*H_ + kc*8;
#pragma unroll
    for (int ks = 0; ks < 32; ++ks) wf[ks] = *reinterpret_cast<const s16x8*>(wp + ks*32);
  }

  auto stage = [&](const u16* src) {            // poll 32KB until sentinel-free, write LDS
    s16x8 stg[8];
#pragma unroll
    for (int r = 0; r < 8; ++r) sc_load16(stg[r], src + (size_t)(tid + r*256)*8);
    wait_vm0();
    for (;;) {
      unsigned dirty = 0;
#pragma unroll
      for (int r = 0; r < 8; ++r) {
        bool bad = false;
#pragma unroll
        for (int j = 0; j < 8; ++j) bad |= (((unsigned)(unsigned short)stg[r][j]) == 0xFFFFu);
        if (bad) dirty |= (1u << r);
      }
      if (!dirty) break;
#pragma unroll
      for (int r = 0; r < 8; ++r)
        if (dirty & (1u << r)) sc_load16(stg[r], src + (size_t)(tid + r*256)*8);
      wait_vm0();
    }
#pragma unroll
    for (int r = 0; r < 8; ++r) {
      int idx8 = tid + r*256;
      int bt = idx8 >> 7, c8 = idx8 & 127;
      *reinterpret_cast<s16x8*>(reinterpret_cast<char*>(sh) +
          bt*2048 + ((c8*16) ^ ((bt & 7) << 4))) = stg[r];
    }
  };

  const int swz = (bcol & 7) << 4;
  auto hfrag = [&](int ks) -> s16x8 {
    return *reinterpret_cast<const s16x8*>(
        reinterpret_cast<const char*>(sh) + bcol*2048 + (((kc*16) + ks*64) ^ swz));
  };
  auto mfma32 = [&](f32x4& a0, f32x4& a1, f32x4& a2, f32x4& a3) {
#pragma unroll
    for (int ks = 0; ks < 32; ks += 4) {
      a0 = __builtin_amdgcn_mfma_f32_16x16x32_bf16(wf[ks+0], hfrag(ks+0), a0, 0, 0, 0);
      a1 = __builtin_amdgcn_mfma_f32_16x16x32_bf16(wf[ks+1], hfrag(ks+1), a1, 0, 0, 0);
      a2 = __builtin_amdgcn_mfma_f32_16x16x32_bf16(wf[ks+2], hfrag(ks+2), a2, 0, 0, 0);
      a3 = __builtin_amdgcn_mfma_f32_16x16x32_bf16(wf[ks+3], hfrag(ks+3), a3, 0, 0, 0);
    }
  };

  if (role == 0) {
    float bc[4];
#pragma unroll
    for (int r = 0; r < 4; ++r) bc[r] = bih1[i0+r] + bhh1[i0+r];
    float4 xv = *reinterpret_cast<const float4*>(x1 + (size_t)bcol*H_ + i0);
    for (int t = 0; t < S_; ++t) {
      f32x4 a0 = {}, a1 = {}, a2 = {}, a3 = {};
      if (t > 0) {
        stage(h1s + (size_t)(t-1)*(B_*H_));
        __syncthreads();
        mfma32(a0, a1, a2, a3);
      }
      float4 xvn = xv;
      if (t + 1 < S_)
        xvn = *reinterpret_cast<const float4*>(x1 + (size_t)((t+1)*B_ + bcol)*H_ + i0);
      f32x4 tot = (a0 + a1) + (a2 + a3);
      u16x4 o;
      o[0] = f2bf(tanhf(tot[0] + xv.x + bc[0]));
      o[1] = f2bf(tanhf(tot[1] + xv.y + bc[1]));
      o[2] = f2bf(tanhf(tot[2] + xv.z + bc[2]));
      o[3] = f2bf(tanhf(tot[3] + xv.w + bc[3]));
      sc_store8(h1s + (size_t)(t*B_ + bcol)*H_ + i0, o);
      __syncthreads();        // MFMA reads of sh done before next stage overwrites
      xv = xvn;
    }
  } else if (role == 1) {
    float bc[4];
#pragma unroll
    for (int r = 0; r < 4; ++r) bc[r] = bih2[i0+r] + bhh2[i0+r];
    for (int t = 0; t < S_; ++t) {
      stage(h1s + (size_t)t*(B_*H_));
      __syncthreads();
      f32x4 a0 = {}, a1 = {}, a2 = {}, a3 = {};
      mfma32(a0, a1, a2, a3);
      f32x4 tot = (a0 + a1) + (a2 + a3);
      tot[0] += bc[0]; tot[1] += bc[1]; tot[2] += bc[2]; tot[3] += bc[3];
      sc_store16f(u2s + ((size_t)t*B_ + bcol)*H_ + i0, tot);
      __syncthreads();
    }
  } else {
    for (int t = 0; t < S_; ++t) {
      f32x4 a0 = {}, a1 = {}, a2 = {}, a3 = {};
      if (t > 0) stage(h2s + (size_t)(t-1)*(B_*H_));
      // point-to-point u[t] poll: this thread's own 16 bytes
      const float* up = u2s + ((size_t)t*B_ + bcol)*H_ + i0;
      f32x4 uv;
      sc_load16f(uv, up);
      wait_vm0();
      for (;;) {
        bool bad = false;
#pragma unroll
        for (int j = 0; j < 4; ++j) bad |= (__float_as_uint(uv[j]) == 0xFFFFFFFFu);
        if (!bad) break;
        sc_load16f(uv, up);
        wait_vm0();
      }
      if (t > 0) {
        __syncthreads();
        mfma32(a0, a1, a2, a3);
      }
      f32x4 tot = (a0 + a1) + (a2 + a3);
      u16x4 o;
      o[0] = f2bf(tanhf(tot[0] + uv[0]));
      o[1] = f2bf(tanhf(tot[1] + uv[1]));
      o[2] = f2bf(tanhf(tot[2] + uv[2]));
      o[3] = f2bf(tanhf(tot[3] + uv[3]));
      sc_store8(h2s + (size_t)(t*B_ + bcol)*H_ + i0, o);
      __syncthreads();
    }
  }
}

// ---------------- online softmax, one row (32000) per wave, in-place ----------------
__global__ __launch_bounds__(256)
void k_softmax(float* __restrict__ out) {
  const int gw = (blockIdx.x*256 + threadIdx.x) >> 6;
  const int l = threadIdx.x & 63;
  float* row = out + (size_t)gw*V_;
  float m = -3.4e38f, s = 0.f;
  for (int it = 0; it < 125; ++it) {
    float4 v = reinterpret_cast<const float4*>(row)[it*64 + l];
    float cm = fmaxf(fmaxf(v.x, v.y), fmaxf(v.z, v.w));
    float nm = fmaxf(m, cm);
    s = s*__expf(m - nm) + __expf(v.x-nm) + __expf(v.y-nm) + __expf(v.z-nm) + __expf(v.w-nm);
    m = nm;
  }
#pragma unroll
  for (int o = 32; o; o >>= 1) {
    float m2 = __shfl_xor(m, o), s2 = __shfl_xor(s, o);
    float nm = fmaxf(m, m2);
    s = s*__expf(m - nm) + s2*__expf(m2 - nm);
    m = nm;
  }
  const float inv = 1.f / s;
  for (int it = 0; it < 125; ++it) {
    float4 v = reinterpret_cast<const float4*>(row)[it*64 + l];
    float4 p;
    p.x = __expf(v.x - m)*inv; p.y = __expf(v.y - m)*inv;
    p.z = __expf(v.z - m)*inv; p.w = __expf(v.w - m)*inv;
    reinterpret_cast<float4*>(row)[it*64 + l] = p;
  }
}

extern "C" void kernel_launch(void* const* d_in, const int* in_sizes, int n_in,
                              void* d_out, int out_size, void* d_ws, size_t ws_size,
                              hipStream_t stream) {
  (void)in_sizes; (void)n_in; (void)out_size; (void)ws_size;
  const int*   x_ids = (const int*)  d_in[0];
  const float* emb   = (const float*)d_in[1];
  const float* Wih1  = (const float*)d_in[2];
  const float* bih1  = (const float*)d_in[3];
  const float* Whh1  = (const float*)d_in[4];
  const float* bhh1  = (const float*)d_in[5];
  const float* Wih2  = (const float*)d_in[6];
  const float* bih2  = (const float*)d_in[7];
  const float* Whh2  = (const float*)d_in[8];
  const float* bhh2  = (const float*)d_in[9];
  const float* Wfc   = (const float*)d_in[10];
  const float* bfc   = (const float*)d_in[11];
  float* out = (float*)d_out;

  char* ws = (char*)d_ws;
  size_t off = 0;
  auto alloc = [&](size_t bytes) {
    char* p = ws + off; off += (bytes + 255) & ~(size_t)255; return p;
  };
  // region A: u2s (16.8 MB) overlaid with {A1 (4MB), Wih1b (1MB)} — both dead
  // before the scan (which is when u2s goes live).
  char* regionA = alloc((size_t)M_TOK*H_*4);
  float* u2s  = (float*)regionA;
  u16* A1     = (u16*)regionA;
  u16* Wih1b  = (u16*)(regionA + (size_t)M_TOK*E_*2);
  u16* Whh1b  = (u16*) alloc((size_t)H_*H_*2);
  u16* Wih2b  = (u16*) alloc((size_t)H_*H_*2);
  u16* Whh2b  = (u16*) alloc((size_t)H_*H_*2);
  u16* Wfcb   = (u16*) alloc((size_t)V_*H_*2);
  float* x1   = (float*)alloc((size_t)M_TOK*H_*4);
  u16* h1s    = (u16*) alloc((size_t)M_TOK*H_*2);
  u16* h2s    = (u16*) alloc((size_t)M_TOK*H_*2);
  // total ≈ 122 MiB (≤ 127 MiB proven in R0/R1)

  k_cvt<<<256,  256, 0, stream>>>(Wih1, Wih1b, H_*E_/4);
  k_cvt<<<256,  256, 0, stream>>>(Whh1, Whh1b, H_*H_/4);
  k_cvt<<<256,  256, 0, stream>>>(Wih2, Wih2b, H_*H_/4);
  k_cvt<<<256,  256, 0, stream>>>(Whh2, Whh2b, H_*H_/4);
  k_cvt<<<2048, 256, 0, stream>>>(Wfc,  Wfcb,  V_*H_/4);
  k_embed<<<M_TOK*64/256, 256, 0, stream>>>(x_ids, emb, A1);

  k_gemm<0><<<dim3(H_/BN, M_TOK/BM), 256, 0, stream>>>(A1, Wih1b, x1, nullptr, M_TOK, H_, E_);

  // NaN-poison exchange buffers (A1/Wih1b now dead), then the fused scan
  hipMemsetAsync(u2s, 0xFF, (size_t)M_TOK*H_*4, stream);
  hipMemsetAsync(h1s, 0xFF, (size_t)M_TOK*H_*2, stream);
  hipMemsetAsync(h2s, 0xFF, (size_t)M_TOK*H_*2, stream);
  k_scan3<<<48, 256, 0, stream>>>(Whh1b, Wih2b, Whh2b, x1,
                                  bih1, bhh1, bih2, bhh2, h1s, h2s, u2s);

  k_gemm<1><<<dim3(V_/BN, M_TOK/BM), 256, 0, stream>>>(h2s, Wfcb, out, bfc, M_TOK, V_, H_);
  k_softmax<<<M_TOK/4, 256, 0, stream>>>(out);
}